// Round 2
// 635.247 us; speedup vs baseline: 1.0857x; 1.0857x over previous
//
#include <hip/hip_runtime.h>
#include <stdint.h>
#include <stddef.h>

typedef __bf16 bf16;
typedef __attribute__((ext_vector_type(8))) __bf16 bf16x8;
typedef __attribute__((ext_vector_type(4))) __bf16 bf16x4;
typedef __attribute__((ext_vector_type(4))) float f32x4;

#define ATT_EPS 1e-6f

// async global->LDS, 16B per lane; LDS dest = wave-uniform base + lane*16
__device__ __forceinline__ void lds16(const void* g, void* l) {
    __builtin_amdgcn_global_load_lds(
        (const __attribute__((address_space(1))) void*)g,
        (__attribute__((address_space(3))) void*)l, 16, 0, 0);
}

// ---------------------------------------------------------------------------
__global__ __launch_bounds__(256) void cvt_bf16(const float4* __restrict__ in,
                                                bf16x4* __restrict__ out, int n4) {
    int i = blockIdx.x * 256 + threadIdx.x;
    if (i < n4) {
        float4 v = in[i];
        bf16x4 o;
        o.x = (bf16)v.x; o.y = (bf16)v.y; o.z = (bf16)v.z; o.w = (bf16)v.w;
        out[i] = o;
    }
}

// ---------------------------------------------------------------------------
__global__ __launch_bounds__(256) void transpose_w(const float* __restrict__ W,
                                                   bf16* __restrict__ Wt) {
    __shared__ float tile[32][33];
    const int bx = blockIdx.x * 32, by = blockIdx.y * 32;
    const int tx = threadIdx.x, ty = threadIdx.y; // 32 x 8
#pragma unroll
    for (int j = 0; j < 32; j += 8)
        tile[ty + j][tx] = W[(size_t)(by + ty + j) * 1024 + bx + tx];
    __syncthreads();
#pragma unroll
    for (int j = 0; j < 32; j += 8)
        Wt[(size_t)(bx + ty + j) * 1024 + by + tx] = (bf16)tile[tx][ty + j];
}

// ---------------------------------------------------------------------------
// 256x256 tile GEMM, C[m][n] = sum_k A[m][k]*B[n][k].
// 512 threads = 8 waves (2M x 4N), per-wave 128x64 output, BK=32.
// 4-stage circular LDS buffer (4 x 32KB = 128KB), counted vmcnt(8) pipeline
// (never drains to 0 in steady state), st_16x32 LDS swizzle applied via
// pre-swizzled global_load_lds SOURCE + swizzled ds_read (involution on
// byte-bit-5 keyed by byte-bit-9, both sides). One s_barrier per K-step,
// s_setprio around the MFMA cluster.
// MODE: 0 = fp32 direct store, 1 = bf16 (LDS-repacked vector store),
//       2 = phi(x)=elu+1 then bf16.
// fast_m: small grid dim is the fast index (XCD L2 locality), fl2 = log2(it).
// ---------------------------------------------------------------------------
template <int MODE>
__global__ __launch_bounds__(512) void gemm256(const bf16* __restrict__ A, int lda,
                                               const bf16* __restrict__ B, int ldb,
                                               void* __restrict__ C, int ldc,
                                               int K, int fast_m, int fl2) {
    __shared__ bf16 smem[65536] __attribute__((aligned(16))); // 128 KiB
    const int t = threadIdx.x;
    const int wave = t >> 6, lane = t & 63;
    // bijective XCD-chunked swizzle (gridDim.x % 8 == 0)
    const int q8 = gridDim.x >> 3;
    const int wg = (blockIdx.x & 7) * q8 + (blockIdx.x >> 3);
    const int f = wg & ((1 << fl2) - 1), s = wg >> fl2;
    const int mt = fast_m ? f : s, nt = fast_m ? s : f;
    const int tileM = mt << 8, tileN = nt << 8;
    const int wm = wave >> 2, wn = wave & 3; // 2 x 4 wave grid

    // staging coords: LDS linear off -> (row, col) of the st_16x32-swizzled
    // layout ([16][32] bf16 subtiles of 1024B, byte ^= ((byte>>9)&1)<<5)
    int rowS[2], colS[2];
#pragma unroll
    for (int j = 0; j < 2; j++) {
        int off = t * 16 + j * 8192;
        int o = off & 1023;
        int op = o ^ (((o >> 9) & 1) << 5);
        rowS[j] = (off >> 10) * 16 + (op >> 6);
        colS[j] = (op & 63) >> 1; // bf16 elems, multiple of 8 (16B aligned)
    }
    const int rm = lane & 15, qq = lane >> 4;
    // fragment read offset inside a subtile (bf16 units), same involution
    const int foff = ((rm * 64 + qq * 16) ^ ((rm >> 3) << 5)) >> 1;

    f32x4 acc[8][4] = {};

#define STAGE(tt)                                                              \
    {                                                                          \
        bf16* sA_ = smem + ((tt) & 3) * 16384;                                 \
        bf16* sB_ = sA_ + 8192;                                                \
        const int k0_ = (tt) << 5;                                             \
        _Pragma("unroll") for (int j = 0; j < 2; j++) {                        \
            lds16(A + (size_t)(tileM + rowS[j]) * lda + k0_ + colS[j],         \
                  sA_ + wave * 512 + j * 4096);                                \
            lds16(B + (size_t)(tileN + rowS[j]) * ldb + k0_ + colS[j],         \
                  sB_ + wave * 512 + j * 4096);                                \
        }                                                                      \
    }

#define COMPUTE(tt)                                                            \
    {                                                                          \
        const bf16* pA_ = smem + ((tt) & 3) * 16384 + wm * 4096 + foff;        \
        const bf16* pB_ = smem + ((tt) & 3) * 16384 + 8192 + wn * 2048 + foff; \
        bf16x8 af_[8], bv_[4];                                                 \
        _Pragma("unroll") for (int mi = 0; mi < 8; mi++)                       \
            af_[mi] = *(const bf16x8*)(pA_ + mi * 512);                        \
        _Pragma("unroll") for (int ni = 0; ni < 4; ni++)                       \
            bv_[ni] = *(const bf16x8*)(pB_ + ni * 512);                        \
        __builtin_amdgcn_s_setprio(1);                                         \
        _Pragma("unroll") for (int mi = 0; mi < 8; mi++)                       \
            _Pragma("unroll") for (int ni = 0; ni < 4; ni++)                   \
                acc[mi][ni] = __builtin_amdgcn_mfma_f32_16x16x32_bf16(         \
                    af_[mi], bv_[ni], acc[mi][ni], 0, 0, 0);                   \
        __builtin_amdgcn_s_setprio(0);                                         \
    }

#define SYNCV(n)                                                               \
    asm volatile("s_waitcnt vmcnt(" #n ")" ::: "memory");                      \
    __builtin_amdgcn_s_barrier();                                              \
    __builtin_amdgcn_sched_barrier(0);

    const int NT = K >> 5; // >= 4 (K = 1024 here)
    STAGE(0); STAGE(1); STAGE(2);
    SYNCV(8); // tile 0 resident; tiles 1,2 in flight
    for (int tt = 0; tt < NT - 3; ++tt) {
        STAGE(tt + 3); // writes buffer of tile tt-1: reads done pre-barrier
        COMPUTE(tt);
        SYNCV(8); // tile tt+1 resident; tt+2, tt+3 stay in flight
    }
    COMPUTE(NT - 3); SYNCV(4);
    COMPUTE(NT - 2); SYNCV(0);
    COMPUTE(NT - 1);
#undef STAGE
#undef COMPUTE
#undef SYNCV

    const int row0 = (lane >> 4) * 4, col = lane & 15;
    if (MODE == 0) {
        float* Cf = (float*)C;
#pragma unroll
        for (int mi = 0; mi < 8; mi++)
#pragma unroll
            for (int ni = 0; ni < 4; ni++)
#pragma unroll
                for (int r = 0; r < 4; r++) {
                    int gm = tileM + wm * 128 + mi * 16 + row0 + r;
                    int gn = tileN + wn * 64 + ni * 16 + col;
                    Cf[(size_t)gm * ldc + gn] = acc[mi][ni][r];
                }
    } else {
        // repack 256x256 bf16 tile in LDS (stride 256, exactly 128 KiB,
        // bijective), then 512B-row vector stores.
        __syncthreads(); // slow waves may still ds_read buffer 3
        bf16* Cb = (bf16*)C;
#pragma unroll
        for (int mi = 0; mi < 8; mi++)
#pragma unroll
            for (int ni = 0; ni < 4; ni++)
#pragma unroll
                for (int r = 0; r < 4; r++) {
                    float v = acc[mi][ni][r];
                    if (MODE == 2) v = (v > 0.f) ? (v + 1.f) : __expf(v);
                    smem[(wm * 128 + mi * 16 + row0 + r) * 256 +
                         wn * 64 + ni * 16 + col] = (bf16)v;
                }
        __syncthreads();
#pragma unroll
        for (int i = 0; i < 16; i++) {
            int c = t + i * 512;
            int row = c >> 5, cb = (c & 31) * 8;
            *(bf16x8*)&Cb[(size_t)(tileM + row) * ldc + tileN + cb] =
                *(const bf16x8*)&smem[row * 256 + cb];
        }
    }
}

// ---------------------------------------------------------------------------
// Phase 2: per (b,h): KvT[n][m] += sum_l Kf[l][m] V[l][n];  row 64 = K1
// ---------------------------------------------------------------------------
__global__ __launch_bounds__(256) void kv_reduce(const bf16* __restrict__ Kft,
                                                 const bf16* __restrict__ Vt,
                                                 float* __restrict__ Kv) {
    const int chunk = blockIdx.x; // 0..7
    const int bh = blockIdx.y;    // 0..63
    const int b = bh >> 4, h = bh & 15;
    __shared__ bf16 sA[64 * 32] __attribute__((aligned(16)));
    __shared__ bf16 sB[64 * 32] __attribute__((aligned(16)));
    const int t = threadIdx.x, wave = t >> 6, lane = t & 63;
    const size_t cbase = (size_t)b * 8192 + (size_t)chunk * 1024;
    const int srow = t >> 2, scol = (t & 3) * 8;
    const bf16* a0 = Kft + (size_t)(h * 64 + srow) * 32768 + cbase + scol;
    const bf16* b0 = Vt + (size_t)(h * 64 + srow) * 32768 + cbase + scol;
    bf16* dA = sA + wave * 512;
    bf16* dB = sB + wave * 512;
    const int rm = lane & 15, qk = (lane >> 4) * 8;

    f32x4 acc[4] = {};
    f32x4 acc1 = {0.f, 0.f, 0.f, 0.f};
    bf16x8 ones;
#pragma unroll
    for (int j = 0; j < 8; j++) ones[j] = (bf16)1.0f;

    for (int k0 = 0; k0 < 1024; k0 += 32) {
        lds16(a0 + k0, dA);
        lds16(b0 + k0, dB);
        __builtin_amdgcn_s_waitcnt(0);
        __syncthreads();
        bf16x8 af = *(const bf16x8*)&sA[(wave * 16 + rm) * 32 + qk];
        bf16x8 bfr[4];
#pragma unroll
        for (int ni = 0; ni < 4; ni++)
            bfr[ni] = *(const bf16x8*)&sB[(ni * 16 + rm) * 32 + qk];
#pragma unroll
        for (int ni = 0; ni < 4; ni++)
            acc[ni] = __builtin_amdgcn_mfma_f32_16x16x32_bf16(af, bfr[ni], acc[ni], 0, 0, 0);
        acc1 = __builtin_amdgcn_mfma_f32_16x16x32_bf16(af, ones, acc1, 0, 0, 0);
        __syncthreads();
    }

    float* out = Kv + bh * 65 * 64;
    const int row0 = (lane >> 4) * 4, col = lane & 15;
    const int m0 = wave * 16 + row0;
#pragma unroll
    for (int ni = 0; ni < 4; ni++)
#pragma unroll
        for (int r = 0; r < 4; r++)
            atomicAdd(&out[(ni * 16 + col) * 64 + m0 + r], acc[ni][r]);
    if (col == 0) {
#pragma unroll
        for (int r = 0; r < 4; r++) atomicAdd(&out[64 * 64 + m0 + r], acc1[r]);
    }
}

// ---------------------------------------------------------------------------
// Phase 3: attn = num/den, LDS-repacked vector epilogue.
// ---------------------------------------------------------------------------
__global__ __launch_bounds__(256) void attn_out(const bf16* __restrict__ Qf,
                                                const float* __restrict__ Kv,
                                                bf16* __restrict__ attn) {
    const int lt = blockIdx.x; // 0..63
    const int bh = blockIdx.y; // 0..63
    const int b = bh >> 4, h = bh & 15;
    constexpr int EP_STRIDE = 80;
    __shared__ bf16 smem[13312] __attribute__((aligned(16)));
    __shared__ float den[128];
    bf16* sQ = smem;
    bf16* sB = smem + 8192;
    const int t = threadIdx.x, wave = t >> 6, lane = t & 63;
    const int qrow = t >> 3, qc = (t & 7) * 8;
    const bf16* qp = Qf + (size_t)(b * 8192 + lt * 128 + qrow) * 1024 + h * 64 + qc;
#pragma unroll
    for (int i = 0; i < 4; i++)
        lds16(qp + (size_t)i * 32 * 1024, sQ + i * 2048 + wave * 512);
    const float* kv = Kv + bh * 65 * 64;
    for (int idx = t; idx < 80 * 64; idx += 256) {
        int n = idx >> 6, k2 = idx & 63;
        sB[idx] = (n < 65) ? (bf16)kv[n * 64 + k2] : (bf16)0.f;
    }
    __builtin_amdgcn_s_waitcnt(0);
    __syncthreads();

    f32x4 acc[2][5] = {};
    const int rm = lane & 15, qk = (lane >> 4) * 8;
#pragma unroll
    for (int k0 = 0; k0 < 64; k0 += 32) {
        bf16x8 af[2], bfr[5];
#pragma unroll
        for (int mi = 0; mi < 2; mi++)
            af[mi] = *(const bf16x8*)&sQ[(wave * 32 + mi * 16 + rm) * 64 + k0 + qk];
#pragma unroll
        for (int ni = 0; ni < 5; ni++)
            bfr[ni] = *(const bf16x8*)&sB[(ni * 16 + rm) * 64 + k0 + qk];
#pragma unroll
        for (int mi = 0; mi < 2; mi++)
#pragma unroll
            for (int ni = 0; ni < 5; ni++)
                acc[mi][ni] = __builtin_amdgcn_mfma_f32_16x16x32_bf16(
                    af[mi], bfr[ni], acc[mi][ni], 0, 0, 0);
    }

    const int row0 = (lane >> 4) * 4, col = lane & 15;
    if (col == 0) {
#pragma unroll
        for (int mi = 0; mi < 2; mi++)
#pragma unroll
            for (int r = 0; r < 4; r++)
                den[wave * 32 + mi * 16 + row0 + r] = acc[mi][4][r] + ATT_EPS;
    }
    __syncthreads();
#pragma unroll
    for (int mi = 0; mi < 2; mi++)
#pragma unroll
        for (int ni = 0; ni < 4; ni++)
#pragma unroll
            for (int r = 0; r < 4; r++) {
                int rl = wave * 32 + mi * 16 + row0 + r;
                smem[rl * EP_STRIDE + ni * 16 + col] =
                    (bf16)(acc[mi][ni][r] / den[rl]);
            }
    __syncthreads();
    const int er = t >> 3, ec = (t & 7) * 8;
#pragma unroll
    for (int i = 0; i < 4; i++) {
        int row = er + i * 32;
        *(bf16x8*)&attn[(size_t)(b * 8192 + lt * 128 + row) * 1024 + h * 64 + ec] =
            *(const bf16x8*)&smem[row * EP_STRIDE + ec];
    }
}

// ---------------------------------------------------------------------------
extern "C" void kernel_launch(void* const* d_in, const int* in_sizes, int n_in,
                              void* d_out, int out_size, void* d_ws, size_t ws_size,
                              hipStream_t stream) {
    const float* x  = (const float*)d_in[0];
    const float* Wq = (const float*)d_in[1];
    const float* Wk = (const float*)d_in[2];
    const float* Wv = (const float*)d_in[3];
    const float* Wo = (const float*)d_in[4];

    char* ws = (char*)d_ws;
    bf16* xb  = (bf16*)ws;                           // 64 MB, reused as attn
    bf16* Qf  = (bf16*)(ws + ((size_t)64 << 20));    // 64 MB
    bf16* Kft = (bf16*)(ws + ((size_t)128 << 20));   // 64 MB
    bf16* Vt  = (bf16*)(ws + ((size_t)192 << 20));   // 64 MB
    bf16* Wqt = (bf16*)(ws + ((size_t)256 << 20));   // 2 MB each
    bf16* Wkt = Wqt + 1024 * 1024;
    bf16* Wvt = Wkt + 1024 * 1024;
    bf16* Wot = Wvt + 1024 * 1024;
    float* Kv = (float*)(Wot + 1024 * 1024);         // 64*65*64 fp32
    bf16* attn = xb;

    cvt_bf16<<<8388608 / 256, 256, 0, stream>>>((const float4*)x, (bf16x4*)xb, 8388608);
    dim3 tb(32, 8);
    transpose_w<<<dim3(32, 32), tb, 0, stream>>>(Wq, Wqt);
    transpose_w<<<dim3(32, 32), tb, 0, stream>>>(Wk, Wkt);
    transpose_w<<<dim3(32, 32), tb, 0, stream>>>(Wv, Wvt);
    transpose_w<<<dim3(32, 32), tb, 0, stream>>>(Wo, Wot);
    hipMemsetAsync(Kv, 0, (size_t)64 * 65 * 64 * sizeof(float), stream);

    // Qf = phi(x @ Wq): M=32768 (128 tiles), N=1024 (4 tiles, fast)
    gemm256<2><<<512, 512, 0, stream>>>(xb, 1024, Wqt, 1024, Qf, 1024, 1024, 0, 2);
    // Kft = phi(Wk^T x^T): M=1024 (4 tiles, fast), N=32768 (128 tiles)
    gemm256<2><<<512, 512, 0, stream>>>(Wkt, 1024, xb, 1024, Kft, 32768, 1024, 1, 2);
    // Vt = Wv^T x^T
    gemm256<1><<<512, 512, 0, stream>>>(Wvt, 1024, xb, 1024, Vt, 32768, 1024, 1, 2);
    // KvT (+K1 row) per (b,h), 8 l-chunks
    kv_reduce<<<dim3(8, 64), 256, 0, stream>>>(Kft, Vt, Kv);
    // attn = num/den (into xb)
    attn_out<<<dim3(64, 64), 256, 0, stream>>>(Qf, Kv, attn);
    // out = attn @ Wo (fp32), N fast
    gemm256<0><<<512, 512, 0, stream>>>(attn, 1024, Wot, 1024, d_out, 1024, 1024, 0, 2);
}